// Round 1
// baseline (122.752 us; speedup 1.0000x reference)
//
#include <hip/hip_runtime.h>
#include <hip/hip_bf16.h>

typedef float  f32x4 __attribute__((ext_vector_type(4)));
typedef _Float16 f16x8 __attribute__((ext_vector_type(8)));

#define NN 4096
#define INF_ 256
#define OUTF 64
#define NH 4
#define LOG2E 1.4426950408889634f

// ---------------------------------------------------------------------------
// K1: Wh = x @ W  (per head), write WhT[h][o][n] as f16, and
//     s_src/s_dst[h][n] = log2e * (Wh . a_src/dst)  (log2-domain scores)
// 512 blocks x 256 threads; block handles 8 nodes; thread = (h, o).
// ---------------------------------------------------------------------------
__global__ __launch_bounds__(256) void k1_wh(
    const float* __restrict__ x, const float* __restrict__ W,
    const float* __restrict__ a, _Float16* __restrict__ whT,
    float* __restrict__ s_src, float* __restrict__ s_dst)
{
    const int n0 = blockIdx.x * 8;
    const int t = threadIdx.x;
    const int h = t >> 6, o = t & 63, lane = t & 63;

    float acc[8] = {0.f,0.f,0.f,0.f,0.f,0.f,0.f,0.f};
    const float* wp = W + h * INF_ * OUTF + o;

    for (int d = 0; d < INF_; d += 4) {
        float w0 = wp[(d+0)*OUTF];
        float w1 = wp[(d+1)*OUTF];
        float w2 = wp[(d+2)*OUTF];
        float w3 = wp[(d+3)*OUTF];
#pragma unroll
        for (int nn = 0; nn < 8; ++nn) {
            float4 xv = *reinterpret_cast<const float4*>(x + (n0+nn)*INF_ + d);
            acc[nn] += xv.x*w0 + xv.y*w1 + xv.z*w2 + xv.w*w3;
        }
    }

    // write WhT f16: 8 consecutive n per thread = one 16B store
    f16x8 hv;
#pragma unroll
    for (int nn = 0; nn < 8; ++nn) hv[nn] = (_Float16)acc[nn];
    *reinterpret_cast<f16x8*>(whT + (h*OUTF + o)*NN + n0) = hv;

    const float asrc = a[h*128 + o];
    const float adst = a[h*128 + 64 + o];
#pragma unroll
    for (int nn = 0; nn < 8; ++nn) {
        float vs = acc[nn] * asrc;
        float vd = acc[nn] * adst;
#pragma unroll
        for (int m = 1; m <= 32; m <<= 1) {
            vs += __shfl_xor(vs, m);
            vd += __shfl_xor(vd, m);
        }
        if (lane == 0) {
            s_src[h*NN + n0 + nn] = LOG2E * vs;
            s_dst[h*NN + n0 + nn] = LOG2E * vd;
        }
    }
}

// ---------------------------------------------------------------------------
// K2: smax[h] = max_n s_dst[h][n]   (global upper bound for row max)
// ---------------------------------------------------------------------------
__global__ __launch_bounds__(256) void k2_smax(const float* __restrict__ s_dst,
                                               float* __restrict__ smax)
{
    const int t = threadIdx.x;
    const int h = t >> 6, lane = t & 63;
    float m = -3.0e38f;
#pragma unroll
    for (int k = 0; k < 16; ++k) {
        float4 v = *reinterpret_cast<const float4*>(s_dst + h*NN + k*256 + lane*4);
        m = fmaxf(m, fmaxf(fmaxf(v.x, v.y), fmaxf(v.z, v.w)));
    }
#pragma unroll
    for (int mm = 1; mm <= 32; mm <<= 1) m = fmaxf(m, __shfl_xor(m, mm));
    if (lane == 0) smax[h] = m;
}

// ---------------------------------------------------------------------------
// K3: fused masked-softmax + P@Wh.
// Grid: 256 blocks = 128 i-tiles(32 rows) x 2 j-halves(2048).
// Block: 512 threads = 8 waves = 4 heads x 2 row-halves(16 rows).
// Softmax uses fixed per-row bound m = LR(s_i + smax) (log2 domain):
//   p = exp2(LR(s_i+s_j) - m) in (0,1], no rescaling needed; the two
//   j-half partials are directly addable (atomicAdd into zeroed d_out).
// P computed in-register directly in the MFMA A-fragment layout.
// ---------------------------------------------------------------------------
__global__ __launch_bounds__(512) void k3_attn(
    const float* __restrict__ adj, const _Float16* __restrict__ whT,
    const float* __restrict__ s_src, const float* __restrict__ s_dst,
    const float* __restrict__ smax, float* __restrict__ out,
    float* __restrict__ l_ws)
{
    __shared__ __align__(16) float    adj_lds[32][36];   // +4 pad: conflict-free
    __shared__ __align__(16) float    s2_lds[NH][32];
    __shared__ __align__(16) _Float16 wh_lds[256][40];   // [h*64+o][32 j + 8 pad]

    const int blk = blockIdx.x;
    const int it  = blk >> 1;
    const int jh  = blk & 1;
    const int t   = threadIdx.x;
    const int w   = t >> 6;
    const int lane = t & 63;
    const int h   = w & 3;
    const int rh  = w >> 2;
    const int row16 = lane & 15;
    const int quad  = lane >> 4;

    const int i0 = it * 32;
    const int jbase0 = jh * 2048;

    const float sI2 = s_src[h*NN + i0 + rh*16 + row16];
    const float zb  = sI2 + smax[h];
    const float mb2 = fmaxf(zb, 0.2f * zb);   // row bound (log2 domain)

    f32x4 acc[4];
#pragma unroll
    for (int ob = 0; ob < 4; ++ob) { acc[ob][0]=0.f; acc[ob][1]=0.f; acc[ob][2]=0.f; acc[ob][3]=0.f; }
    float lsum = 0.f;

    // staging indices
    const int srow = t >> 4;          // 0..31
    const int sc2  = (t & 15) * 2;    // 0,2,..,30
    const int ho   = t >> 1;          // 0..255
    const int part = t & 1;

    for (int s = 0; s < 64; ++s) {
        const int jb = jbase0 + s * 32;
        __syncthreads();
        // ---- stage adj tile (32 rows x 32 j), patch diagonal to 1 ----
        {
            float2 v = *reinterpret_cast<const float2*>(adj + (size_t)(i0 + srow)*NN + jb + sc2);
            const int gi = i0 + srow;
            if (gi == jb + sc2)     v.x = 1.0f;
            if (gi == jb + sc2 + 1) v.y = 1.0f;
            adj_lds[srow][sc2]   = v.x;
            adj_lds[srow][sc2+1] = v.y;
        }
        // ---- stage s_dst tile (4 heads x 32) ----
        if (t < 128) s2_lds[t>>5][t&31] = s_dst[(t>>5)*NN + jb + (t&31)];
        // ---- stage Wh tile (256 (h,o)-rows x 32 j), 32B per thread ----
        {
            const f16x8* src = reinterpret_cast<const f16x8*>(whT + ho*NN + jb + part*16);
            f16x8 v0 = src[0], v1 = src[1];
            *reinterpret_cast<f16x8*>(&wh_lds[ho][part*16])     = v0;
            *reinterpret_cast<f16x8*>(&wh_lds[ho][part*16 + 8]) = v1;
        }
        __syncthreads();

        // ---- compute P fragment (A layout: row=lane&15, k=quad*8+e) ----
        float4 sj0 = *reinterpret_cast<const float4*>(&s2_lds[h][quad*8]);
        float4 sj1 = *reinterpret_cast<const float4*>(&s2_lds[h][quad*8+4]);
        float4 av0 = *reinterpret_cast<const float4*>(&adj_lds[rh*16+row16][quad*8]);
        float4 av1 = *reinterpret_cast<const float4*>(&adj_lds[rh*16+row16][quad*8+4]);
        float sjv[8] = {sj0.x,sj0.y,sj0.z,sj0.w,sj1.x,sj1.y,sj1.z,sj1.w};
        float adv[8] = {av0.x,av0.y,av0.z,av0.w,av1.x,av1.y,av1.z,av1.w};
        f16x8 pa;
#pragma unroll
        for (int e = 0; e < 8; ++e) {
            float z  = sI2 + sjv[e];
            float el = fmaxf(z, 0.2f * z);                 // leaky relu (log2 dom.)
            float p  = (adv[e] != 0.0f) ? __builtin_amdgcn_exp2f(el - mb2) : 0.0f;
            lsum += p;
            pa[e] = (_Float16)p;
        }
        // ---- 4 MFMAs: 16(rows) x 64(outs) x 32(j) ----
#pragma unroll
        for (int ob = 0; ob < 4; ++ob) {
            f16x8 bf = *reinterpret_cast<const f16x8*>(&wh_lds[h*64 + ob*16 + row16][quad*8]);
            acc[ob] = __builtin_amdgcn_mfma_f32_16x16x32_f16(pa, bf, acc[ob], 0, 0, 0);
        }
    }

    // ---- epilogue: reduce l over the 4 quads, store partials ----
    lsum += __shfl_xor(lsum, 16);
    lsum += __shfl_xor(lsum, 32);
    if (lane < 16)
        l_ws[(jh*NN + i0 + rh*16 + lane)*NH + h] = lsum;

#pragma unroll
    for (int ob = 0; ob < 4; ++ob) {
#pragma unroll
        for (int q = 0; q < 4; ++q) {
            const int grow = i0 + rh*16 + quad*4 + q;       // C: row=(lane>>4)*4+q
            const int gcol = h*OUTF + ob*16 + row16;        // C: col=lane&15
            atomicAdd(&out[grow*(NH*OUTF) + gcol], acc[ob][q]);
        }
    }
}

// ---------------------------------------------------------------------------
// K4: out = out / (l0 + l1)
// ---------------------------------------------------------------------------
__global__ __launch_bounds__(256) void k4_norm(float* __restrict__ out,
                                               const float* __restrict__ l_ws)
{
    const int idx = blockIdx.x * 256 + threadIdx.x;   // float4 index, < 262144
    const int n  = idx >> 6;
    const int c4 = idx & 63;
    const int h  = c4 >> 4;
    const float L = l_ws[n*NH + h] + l_ws[(NN + n)*NH + h];
    const float inv = 1.0f / L;
    float4 v = reinterpret_cast<float4*>(out)[idx];
    v.x *= inv; v.y *= inv; v.z *= inv; v.w *= inv;
    reinterpret_cast<float4*>(out)[idx] = v;
}

extern "C" void kernel_launch(void* const* d_in, const int* in_sizes, int n_in,
                              void* d_out, int out_size, void* d_ws, size_t ws_size,
                              hipStream_t stream)
{
    const float* x   = (const float*)d_in[0];
    const float* adj = (const float*)d_in[1];
    const float* W   = (const float*)d_in[2];
    const float* a   = (const float*)d_in[3];
    float* out = (float*)d_out;

    // workspace layout (~2.26 MB)
    char* ws = (char*)d_ws;
    _Float16* whT  = (_Float16*)ws;                       // 2 MB
    float* s_src   = (float*)(ws + (2u<<20));             // 64 KB
    float* s_dst   = s_src + NH*NN;                       // 64 KB
    float* smax    = s_dst + NH*NN;                       // 64 B
    float* l_ws    = smax + 16;                           // 128 KB

    hipMemsetAsync(d_out, 0, (size_t)out_size * sizeof(float), stream);
    k1_wh  <<<NN/8, 256, 0, stream>>>(x, W, a, whT, s_src, s_dst);
    k2_smax<<<1,    256, 0, stream>>>(s_dst, smax);
    k3_attn<<<256,  512, 0, stream>>>(adj, whT, s_src, s_dst, smax, out, l_ws);
    k4_norm<<<out_size/4/256, 256, 0, stream>>>(out, l_ws);
}